// Round 2
// baseline (160.208 us; speedup 1.0000x reference)
//
#include <hip/hip_runtime.h>
#include <cstdint>

// MXFP4 fake-quant linear: out = qdq(A) @ qdq(W)^T + bias
// Stage 1: quantize fp32 -> packed e2m1 + e8m0 scales (unchanged, verified).
// Stage 2: fp4 GEMM, 128x128 tile, 256 threads (4 waves 2x2), NBUF=2,
// 3 WGs/CU for cross-WG overlap, XCD-aware block remap for L2-resident
// operands, counted vmcnt, setprio, per-fragment operand builds.

#define BM 128
#define BN 128
#define BK 128      // K elements per pipeline tile = one mfma k-step
#define NBUF 2

typedef float floatx4 __attribute__((ext_vector_type(4)));
typedef int intx8 __attribute__((ext_vector_type(8)));

#define GLOBAL_AS __attribute__((address_space(1)))
#define LDS_AS __attribute__((address_space(3)))

// ---------------- quantize fp32 -> packed fp4 + e8m0 scales ----------------
// Lane i loads contiguous float4; 8 consecutive lanes share one 1x32 block.

__device__ __forceinline__ int enc1(float x, float inv) {
    float q = x * inv;                         // inv = 2^-(e-2), exact
    q = fminf(fmaxf(q, -6.0f), 6.0f);
    int s = (int)(__float_as_uint(q) >> 31) << 3;
    float aq = fabsf(q);
    float ilsb = aq < 2.0f ? 2.0f : (aq < 4.0f ? 1.0f : 0.5f);
    float lsb  = aq < 2.0f ? 0.5f : (aq < 4.0f ? 1.0f : 2.0f);
    float ar = rintf(aq * ilsb) * lsb;         // RNE onto e2m1 grid (symmetric)
    int c;
    if (ar < 2.0f)      c = (int)(ar * 2.0f);  // 0,.5,1,1.5 -> 0..3
    else if (ar < 4.0f) c = 2 + (int)ar;       // 2,3 -> 4,5
    else                c = 4 + (int)(ar * 0.5f); // 4,6 -> 6,7
    return c | s;
}

__global__ void quant_mxfp4_v3(const float* __restrict__ A, uint8_t* __restrict__ Aq,
                               uint8_t* __restrict__ Asc,
                               const float* __restrict__ W, uint8_t* __restrict__ Wq,
                               uint8_t* __restrict__ Wsc,
                               long na4, long ntot4) {
    long t = (long)blockIdx.x * 256 + threadIdx.x;
    if (t >= ntot4) return;
    const float* src; uint8_t* dq; uint8_t* ds; long idx;
    if (t < na4) { src = A; dq = Aq; ds = Asc; idx = t; }
    else         { src = W; dq = Wq; ds = Wsc; idx = t - na4; }

    float4 f = ((const float4*)src)[idx];
    float amax = fmaxf(fmaxf(fabsf(f.x), fabsf(f.y)),
                       fmaxf(fabsf(f.z), fabsf(f.w)));
    amax = fmaxf(amax, __shfl_xor(amax, 1));
    amax = fmaxf(amax, __shfl_xor(amax, 2));
    amax = fmaxf(amax, __shfl_xor(amax, 4));

    int ebits = (int)((__float_as_uint(amax) >> 23) & 0xff);
    int sb;
    float inv;
    if (amax > 0.0f) {
        sb = ebits - 2; if (sb < 0) sb = 0;
        // inv = 2^(129 - ebits) = 2^(2 - e); exact power of two
        inv = __uint_as_float((unsigned)((256 - ebits) & 255) << 23);
    } else {
        sb = 127;              // scale 1.0, all-zero block
        inv = 0.0f;
    }

    int c0 = enc1(f.x, inv), c1 = enc1(f.y, inv);
    int c2 = enc1(f.z, inv), c3 = enc1(f.w, inv);
    // little-endian: elem 2i in low nibble of byte i
    ((unsigned short*)dq)[idx] =
        (unsigned short)(c0 | (c1 << 4) | (c2 << 8) | (c3 << 12));
    if ((idx & 7) == 0) ds[idx >> 3] = (uint8_t)sb;
}

// ---------- fp4 GEMM: C[M,N] = (Aq,As) x (Wq,Ws)^T + bias ----------
// 256 threads = 4 waves in 2(M) x 2(N); per-wave output 64x64 (acc[4][4]).
// A-frag (16x16x128): row = lane&15, k-block = lane>>4 (16B = 32 elems).
// Scale operand: e8m0 byte of the lane's k-block, opsel 0.
// C/D: col(lane&15)=n, row((lane>>4)*4+reg)=m. All verified in round 1.
//
// LDS swizzle: 64B rows of 4x16B chunks; slot c holds global chunk
// c ^ s(row), s(row)=(row^(row>>2))&3 -> 2 lanes/slot per 16-lane group.
//
// XCD remap: id%8 = XCD (round-robin dispatch); we assign by%8 = XCD so all
// 16 bx-blocks sharing an A-panel sit on one XCD. Per-XCD working set =
// 8 A-panels (1 MB) + whole W (2.1 MB) = 3.1 MB < 4 MB L2.

__global__ __launch_bounds__(256, 3) void gemm_fp4_pipe(
        const uint8_t* __restrict__ Aq, const uint8_t* __restrict__ Asc,
        const uint8_t* __restrict__ Wq, const uint8_t* __restrict__ Wsc,
        const float* __restrict__ bias, float* __restrict__ C,
        int M, int N, int K) {
    __shared__ __align__(16) uint8_t sA[NBUF][BM * BK / 2];   // 2 x 8 KB
    __shared__ __align__(16) uint8_t sB[NBUF][BN * BK / 2];   // 2 x 8 KB
    __shared__ __align__(16) uint8_t sSA[NBUF][BM * 4];       // 2 x 512 B
    __shared__ __align__(16) uint8_t sSB[NBUF][BN * 4];       // 2 x 512 B

    const int tid = threadIdx.x;
    const int lane = tid & 63;
    const int w = tid >> 6;
    const int wr = w >> 1;           // 0..1 (M direction)
    const int wc = w & 1;            // 0..1 (N direction)
    const int row16 = lane & 15;
    const int quad = lane >> 4;      // k-block (32 elems) index
    const int shq = quad * 8;

    // XCD-aware bijective remap: g = XCD, by = g + 8*(h&7), bx = h>>3
    const int id = blockIdx.x;
    const int g = id & 7, h = id >> 3;
    const int by = g + 8 * (h & 7);  // 0..63
    const int bx = h >> 3;           // 0..15
    const int m0 = by * BM;
    const int n0 = bx * BN;
    const int KB2 = K >> 1, KB32 = K >> 5;
    const int NT = K / BK;           // 16

    const int fragoff = (quad ^ ((row16 ^ (row16 >> 2)) & 3)) * 16;
    const int rA = wr * 64 + row16;
    const int rB = wc * 64 + row16;

    floatx4 acc[4][4];
#pragma unroll
    for (int i = 0; i < 4; i++)
#pragma unroll
        for (int j = 0; j < 4; j++) acc[i][j] = (floatx4){0.f, 0.f, 0.f, 0.f};

    // 5 vmem insts per wave per tile (uniform; no intra-wave divergence:
    // tid<128 <=> waves 0-1).
    auto stage = [&](int tt) {
        const int bb = tt & 1;
        const int kb = tt * (BK / 2);           // 64 B per tile along K
#pragma unroll
        for (int it = 0; it < 2; ++it) {
            int idx = it * 256 + tid;           // 0..511 16B chunks
            int row = idx >> 2, c = idx & 3;
            int gsw = c ^ ((row ^ (row >> 2)) & 3);
            const uint8_t* src = Aq + (size_t)(m0 + row) * KB2 + kb + gsw * 16;
            __builtin_amdgcn_global_load_lds((GLOBAL_AS void*)src,
                (LDS_AS void*)(&sA[bb][idx * 16]), 16, 0, 0);
        }
#pragma unroll
        for (int it = 0; it < 2; ++it) {
            int idx = it * 256 + tid;
            int row = idx >> 2, c = idx & 3;
            int gsw = c ^ ((row ^ (row >> 2)) & 3);
            const uint8_t* src = Wq + (size_t)(n0 + row) * KB2 + kb + gsw * 16;
            __builtin_amdgcn_global_load_lds((GLOBAL_AS void*)src,
                (LDS_AS void*)(&sB[bb][idx * 16]), 16, 0, 0);
        }
        if (tid < 128) {
            const uint8_t* src = Asc + (size_t)(m0 + tid) * KB32 + tt * 4;
            __builtin_amdgcn_global_load_lds((GLOBAL_AS void*)src,
                (LDS_AS void*)(&sSA[bb][tid * 4]), 4, 0, 0);
        } else {
            const uint8_t* src = Wsc + (size_t)(n0 + tid - 128) * KB32 + tt * 4;
            __builtin_amdgcn_global_load_lds((GLOBAL_AS void*)src,
                (LDS_AS void*)(&sSB[bb][(tid - 128) * 4]), 4, 0, 0);
        }
    };

    // ---- prologue: stage tiles 0,1; wait for tile 0 ----
    stage(0);
    if (NT > 1) stage(1);
    if (NT > 1) asm volatile("s_waitcnt vmcnt(5)" ::: "memory");
    else        asm volatile("s_waitcnt vmcnt(0)" ::: "memory");
    __builtin_amdgcn_sched_barrier(0);
    __builtin_amdgcn_s_barrier();
    __builtin_amdgcn_sched_barrier(0);

    for (int t = 0; t < NT; ++t) {
        const int p = t & 1;
        const uint8_t* pa = sA[p];
        const uint8_t* pb = sB[p];

        // LDS -> register fragments; build 8-wide operands ONCE per frag
        intx8 A8[4], B8[4];
        int sab[4], swb[4];
#pragma unroll
        for (int ni = 0; ni < 4; ++ni) {
            int r = rB + ni * 16;
            int4 f = *(const int4*)(pb + r * 64 + fragoff);
            B8[ni] = (intx8){f.x, f.y, f.z, f.w, 0, 0, 0, 0};
            swb[ni] = (*(const int*)(&sSB[p][r * 4]) >> shq) & 0xff;
        }
#pragma unroll
        for (int mi = 0; mi < 4; ++mi) {
            int r = rA + mi * 16;
            int4 f = *(const int4*)(pa + r * 64 + fragoff);
            A8[mi] = (intx8){f.x, f.y, f.z, f.w, 0, 0, 0, 0};
            sab[mi] = (*(const int*)(&sSA[p][r * 4]) >> shq) & 0xff;
        }

        // all waves done reading buf p before anyone DMAs into it
        asm volatile("s_waitcnt lgkmcnt(0)" ::: "memory");
        __builtin_amdgcn_sched_barrier(0);
        __builtin_amdgcn_s_barrier();
        __builtin_amdgcn_sched_barrier(0);

        if (t + 2 < NT) stage(t + 2);   // prefetch into buf p (just freed)

        __builtin_amdgcn_s_setprio(1);
#pragma unroll
        for (int mi = 0; mi < 4; ++mi) {
#pragma unroll
            for (int ni = 0; ni < 4; ++ni) {
                acc[mi][ni] = __builtin_amdgcn_mfma_scale_f32_16x16x128_f8f6f4(
                    A8[mi], B8[ni], acc[mi][ni], 4, 4, 0, sab[mi], 0, swb[ni]);
            }
        }
        __builtin_amdgcn_s_setprio(0);

        // counted wait: tile t+1 landed; keep t+2 in flight
        if (t < NT - 1) {
            if (t + 2 < NT) asm volatile("s_waitcnt vmcnt(5)" ::: "memory");
            else            asm volatile("s_waitcnt vmcnt(0)" ::: "memory");
            __builtin_amdgcn_sched_barrier(0);
            __builtin_amdgcn_s_barrier();
            __builtin_amdgcn_sched_barrier(0);
        }
    }

    // ---- epilogue: C/D col(lane&15)=n, row(quad*4+reg)=m ----
#pragma unroll
    for (int ni = 0; ni < 4; ++ni) {
        int n = n0 + wc * 64 + ni * 16 + row16;
        float bv = bias[n];
#pragma unroll
        for (int mi = 0; mi < 4; ++mi) {
            int mbase = m0 + wr * 64 + mi * 16 + quad * 4;
#pragma unroll
            for (int r = 0; r < 4; ++r) {
                C[(size_t)(mbase + r) * N + n] = acc[mi][ni][r] + bv;
            }
        }
    }
}

// ---------------- launch ----------------

extern "C" void kernel_launch(void* const* d_in, const int* in_sizes, int n_in,
                              void* d_out, int out_size, void* d_ws, size_t ws_size,
                              hipStream_t stream) {
    const float* inp  = (const float*)d_in[0];
    const float* wgt  = (const float*)d_in[1];
    const float* bias = (const float*)d_in[2];
    float* out = (float*)d_out;

    const int N = in_sizes[2];                 // 2048
    const int K = in_sizes[1] / N;             // 2048
    const long M = (long)in_sizes[0] / K;      // 8192

    uint8_t* Aq4 = (uint8_t*)d_ws;             // M*K/2
    uint8_t* Wq4 = Aq4 + (size_t)M * K / 2;    // N*K/2
    uint8_t* Asc = Wq4 + (size_t)N * K / 2;    // M*K/32
    uint8_t* Wsc = Asc + (size_t)M * K / 32;   // N*K/32

    long na4   = (long)M * K / 4;
    long ntot4 = na4 + (long)N * K / 4;
    quant_mxfp4_v3<<<dim3((ntot4 + 255) / 256), dim3(256), 0, stream>>>(
        inp, Aq4, Asc, wgt, Wq4, Wsc, na4, ntot4);

    dim3 grid((N / BN) * (int)(M / BM));       // 16*64 = 1024 WGs, 3-4/CU
    gemm_fp4_pipe<<<grid, dim3(256), 0, stream>>>(
        Aq4, Asc, Wq4, Wsc, bias, out, (int)M, N, K);
}

// Round 3
// 156.680 us; speedup vs baseline: 1.0225x; 1.0225x over previous
//
#include <hip/hip_runtime.h>
#include <cstdint>

// MXFP4 fake-quant linear: out = qdq(A) @ qdq(W)^T + bias
// Stage 1: quantize fp32 -> packed e2m1 + e8m0 scales. Scales stored
//          TRANSPOSED: AscT[kblk][m], WscT[kblk][n] for coalesced staging.
// Stage 2: fp4 GEMM, 128x128 tile, 256 threads (4 waves 2x2), NBUF=2,
//          grid 1024 at EXACTLY 4 WGs/CU (zero tail), linear LDS,
//          coalesced scale DMA, counted vmcnt, setprio, XCD remap.

#define BM 128
#define BN 128
#define BK 128      // K elements per tile = one mfma_scale k-step

typedef float floatx4 __attribute__((ext_vector_type(4)));
typedef int intx8 __attribute__((ext_vector_type(8)));

#define GLOBAL_AS __attribute__((address_space(1)))
#define LDS_AS __attribute__((address_space(3)))

// ---------------- quantize fp32 -> packed fp4 + e8m0 scales ----------------
// Lane i loads contiguous float4; 8 consecutive lanes share one 1x32 block.

__device__ __forceinline__ int enc1(float x, float inv) {
    float q = x * inv;                         // inv = 2^-(e-2), exact
    q = fminf(fmaxf(q, -6.0f), 6.0f);
    int s = (int)(__float_as_uint(q) >> 31) << 3;
    float aq = fabsf(q);
    float ilsb = aq < 2.0f ? 2.0f : (aq < 4.0f ? 1.0f : 0.5f);
    float lsb  = aq < 2.0f ? 0.5f : (aq < 4.0f ? 1.0f : 2.0f);
    float ar = rintf(aq * ilsb) * lsb;         // RNE onto e2m1 grid
    int c;
    if (ar < 2.0f)      c = (int)(ar * 2.0f);  // 0,.5,1,1.5 -> 0..3
    else if (ar < 4.0f) c = 2 + (int)ar;       // 2,3 -> 4,5
    else                c = 4 + (int)(ar * 0.5f); // 4,6 -> 6,7
    return c | s;
}

__global__ void quant_mxfp4_v4(const float* __restrict__ A, uint8_t* __restrict__ Aq,
                               uint8_t* __restrict__ AscT,
                               const float* __restrict__ W, uint8_t* __restrict__ Wq,
                               uint8_t* __restrict__ WscT,
                               long na4, long ntot4, int s4, long Mr, long Nr) {
    long t = (long)blockIdx.x * 256 + threadIdx.x;
    if (t >= ntot4) return;
    const float* src; uint8_t* dq; uint8_t* ds; long idx; long rows;
    if (t < na4) { src = A; dq = Aq; ds = AscT; idx = t; rows = Mr; }
    else         { src = W; dq = Wq; ds = WscT; idx = t - na4; rows = Nr; }

    float4 f = ((const float4*)src)[idx];
    float amax = fmaxf(fmaxf(fabsf(f.x), fabsf(f.y)),
                       fmaxf(fabsf(f.z), fabsf(f.w)));
    amax = fmaxf(amax, __shfl_xor(amax, 1));
    amax = fmaxf(amax, __shfl_xor(amax, 2));
    amax = fmaxf(amax, __shfl_xor(amax, 4));

    int ebits = (int)((__float_as_uint(amax) >> 23) & 0xff);
    int sb;
    float inv;
    if (amax > 0.0f) {
        sb = ebits - 2; if (sb < 0) sb = 0;
        inv = __uint_as_float((unsigned)((256 - ebits) & 255) << 23);
    } else {
        sb = 127;              // scale 1.0, all-zero block
        inv = 0.0f;
    }

    int c0 = enc1(f.x, inv), c1 = enc1(f.y, inv);
    int c2 = enc1(f.z, inv), c3 = enc1(f.w, inv);
    ((unsigned short*)dq)[idx] =
        (unsigned short)(c0 | (c1 << 4) | (c2 << 8) | (c3 << 12));
    if ((idx & 7) == 0) {
        long m  = idx >> s4;                       // row
        int  kb = (int)((idx & ((1L << s4) - 1)) >> 3);  // k-block (32 elems)
        ds[(size_t)kb * rows + m] = (uint8_t)sb;   // transposed: [kb][row]
    }
}

// ---------- fp4 GEMM: C[M,N] = (Aq,AscT) x (Wq,WscT)^T + bias ----------
// 256 threads = 4 waves 2(M) x 2(N); per-wave output 64x64 (acc[4][4]).
// A-frag (16x16x128): row = lane&15, k-block = lane>>4 (16B = 32 elems).
// C/D: col(lane&15)=n, row((lane>>4)*4+reg)=m. Verified rounds 1-2.
// LDS layout linear (row = 64B): b128 frag reads are naturally balanced
// 8 lanes per 4-bank group (minimum service time) -- no swizzle needed.
// Scales: transposed global layout -> one coalesced 4B/thread DMA per tile
// into sS[2][kb(4)][128+128]; frag scale = ds_read_u8.

__global__ __launch_bounds__(256, 4) void gemm_fp4_v4(
        const uint8_t* __restrict__ Aq, const uint8_t* __restrict__ AscT,
        const uint8_t* __restrict__ Wq, const uint8_t* __restrict__ WscT,
        const float* __restrict__ bias, float* __restrict__ C,
        int M, int N, int K) {
    __shared__ __align__(16) uint8_t sA[2][BM * 64];   // 2 x 8 KB
    __shared__ __align__(16) uint8_t sB[2][BN * 64];   // 2 x 8 KB
    __shared__ __align__(16) uint8_t sSA[2][4 * 128];  // 2 x 512 B  [kb][m]
    __shared__ __align__(16) uint8_t sSB[2][4 * 128];  // 2 x 512 B  [kb][n]

    const int tid = threadIdx.x;
    const int lane = tid & 63;
    const int w = tid >> 6;
    const int wr = w >> 1;           // 0..1 (M)
    const int wc = w & 1;            // 0..1 (N)
    const int row16 = lane & 15;
    const int quad = lane >> 4;      // k-block index within tile

    // XCD-aware bijective remap (grid 1024, id%8 = XCD)
    const int id = blockIdx.x;
    const int g = id & 7, h = id >> 3;
    const int by = g + 8 * (h & 7);  // 0..63
    const int bx = h >> 3;           // 0..15
    const int m0 = by * BM;
    const int n0 = bx * BN;
    const int KB2 = K >> 1;
    const int NT = K / BK;           // 16

    const int rA = wr * 64 + row16;
    const int rB = wc * 64 + row16;

    floatx4 acc[4][4];
#pragma unroll
    for (int i = 0; i < 4; i++)
#pragma unroll
        for (int j = 0; j < 4; j++) acc[i][j] = (floatx4){0.f, 0.f, 0.f, 0.f};

    // 5 uniform DMA insts per thread per tile: 2 A + 2 B (16B) + 1 scale (4B)
    auto stage = [&](int tt) {
        const int bb = tt & 1;
        const int kb = tt * 64;                 // byte offset along packed K
#pragma unroll
        for (int it = 0; it < 2; ++it) {
            int idx = it * 256 + tid;           // 0..511 16B chunks
            int row = idx >> 2, c = idx & 3;
            const uint8_t* src = Aq + (size_t)(m0 + row) * KB2 + kb + c * 16;
            __builtin_amdgcn_global_load_lds((GLOBAL_AS void*)src,
                (LDS_AS void*)(&sA[bb][idx * 16]), 16, 0, 0);
        }
#pragma unroll
        for (int it = 0; it < 2; ++it) {
            int idx = it * 256 + tid;
            int row = idx >> 2, c = idx & 3;
            const uint8_t* src = Wq + (size_t)(n0 + row) * KB2 + kb + c * 16;
            __builtin_amdgcn_global_load_lds((GLOBAL_AS void*)src,
                (LDS_AS void*)(&sB[bb][idx * 16]), 16, 0, 0);
        }
        // scales: [kb][row] global -> [kb][128] LDS, 4B/thread, coalesced
        if (tid < 128) {
            int kbi = tid >> 5, moff = (tid & 31) * 4;
            const uint8_t* src = AscT + (size_t)(4 * tt + kbi) * M + m0 + moff;
            __builtin_amdgcn_global_load_lds((GLOBAL_AS void*)src,
                (LDS_AS void*)(&sSA[bb][tid * 4]), 4, 0, 0);
        } else {
            int tw = tid - 128;
            int kbi = tw >> 5, noff = (tw & 31) * 4;
            const uint8_t* src = WscT + (size_t)(4 * tt + kbi) * N + n0 + noff;
            __builtin_amdgcn_global_load_lds((GLOBAL_AS void*)src,
                (LDS_AS void*)(&sSB[bb][tw * 4]), 4, 0, 0);
        }
    };

    // ---- prologue: stage tiles 0,1; wait for tile 0 (5 newest in flight) ----
    stage(0);
    stage(1);
    asm volatile("s_waitcnt vmcnt(5)" ::: "memory");
    __builtin_amdgcn_sched_barrier(0);
    __builtin_amdgcn_s_barrier();

    for (int t = 0; t < NT; ++t) {
        const int p = t & 1;
        const uint8_t* pa = sA[p];
        const uint8_t* pb = sB[p];

        // LDS -> register fragments (int4) + scale bytes
        int4 afr[4], bfr[4];
        int sab[4], swb[4];
#pragma unroll
        for (int ni = 0; ni < 4; ++ni) {
            int r = rB + ni * 16;
            bfr[ni] = *(const int4*)(pb + r * 64 + quad * 16);
            swb[ni] = (int)sSB[p][quad * 128 + wc * 64 + ni * 16 + row16];
        }
#pragma unroll
        for (int mi = 0; mi < 4; ++mi) {
            int r = rA + mi * 16;
            afr[mi] = *(const int4*)(pa + r * 64 + quad * 16);
            sab[mi] = (int)sSA[p][quad * 128 + wr * 64 + mi * 16 + row16];
        }

        asm volatile("s_waitcnt lgkmcnt(0)" ::: "memory");
        __builtin_amdgcn_sched_barrier(0);
        __builtin_amdgcn_s_barrier();       // B1: all waves done reading buf p

        if (t + 2 < NT) stage(t + 2);       // overwrite buf p (just freed)

        __builtin_amdgcn_s_setprio(1);
#pragma unroll
        for (int mi = 0; mi < 4; ++mi) {
            intx8 a8 = {afr[mi].x, afr[mi].y, afr[mi].z, afr[mi].w, 0, 0, 0, 0};
#pragma unroll
            for (int ni = 0; ni < 4; ++ni) {
                intx8 b8 = {bfr[ni].x, bfr[ni].y, bfr[ni].z, bfr[ni].w, 0, 0, 0, 0};
                acc[mi][ni] = __builtin_amdgcn_mfma_scale_f32_16x16x128_f8f6f4(
                    a8, b8, acc[mi][ni], 4, 4, 0, sab[mi], 0, swb[ni]);
            }
        }
        __builtin_amdgcn_s_setprio(0);

        // counted wait: tile t+1 landed; keep t+2 (5 insts) in flight
        if (t < NT - 1) {
            if (t + 2 < NT) asm volatile("s_waitcnt vmcnt(5)" ::: "memory");
            else            asm volatile("s_waitcnt vmcnt(0)" ::: "memory");
            __builtin_amdgcn_sched_barrier(0);
            __builtin_amdgcn_s_barrier();   // B2: everyone's t+1 data visible
        }
    }

    // ---- epilogue: C/D col(lane&15)=n, row(quad*4+reg)=m ----
#pragma unroll
    for (int ni = 0; ni < 4; ++ni) {
        int n = n0 + wc * 64 + ni * 16 + row16;
        float bv = bias[n];
#pragma unroll
        for (int mi = 0; mi < 4; ++mi) {
            int mbase = m0 + wr * 64 + mi * 16 + quad * 4;
#pragma unroll
            for (int r = 0; r < 4; ++r) {
                C[(size_t)(mbase + r) * N + n] = acc[mi][ni][r] + bv;
            }
        }
    }
}

// ---------------- launch ----------------

extern "C" void kernel_launch(void* const* d_in, const int* in_sizes, int n_in,
                              void* d_out, int out_size, void* d_ws, size_t ws_size,
                              hipStream_t stream) {
    const float* inp  = (const float*)d_in[0];
    const float* wgt  = (const float*)d_in[1];
    const float* bias = (const float*)d_in[2];
    float* out = (float*)d_out;

    const int N = in_sizes[2];                 // 2048
    const int K = in_sizes[1] / N;             // 2048
    const long M = (long)in_sizes[0] / K;      // 8192

    uint8_t* Aq4  = (uint8_t*)d_ws;            // M*K/2
    uint8_t* Wq4  = Aq4 + (size_t)M * K / 2;   // N*K/2
    uint8_t* AscT = Wq4 + (size_t)N * K / 2;   // M*K/32 (layout [K/32][M])
    uint8_t* WscT = AscT + (size_t)M * K / 32; // N*K/32 (layout [K/32][N])

    int s4 = 0;
    while ((1 << s4) < (K >> 2)) ++s4;         // log2(K/4) = 9

    long na4   = (long)M * K / 4;
    long ntot4 = na4 + (long)N * K / 4;
    quant_mxfp4_v4<<<dim3((ntot4 + 255) / 256), dim3(256), 0, stream>>>(
        inp, Aq4, AscT, wgt, Wq4, WscT, na4, ntot4, s4, M, (long)N);

    dim3 grid((N / BN) * (int)(M / BM));       // 16*64 = 1024 = exactly 4/CU
    gemm_fp4_v4<<<grid, dim3(256), 0, stream>>>(
        Aq4, AscT, Wq4, WscT, bias, out, (int)M, N, K);
}